// Round 1
// baseline (424.619 us; speedup 1.0000x reference)
//
#include <hip/hip_runtime.h>
#include <hip/hip_bf16.h>

typedef __attribute__((ext_vector_type(8))) short bf16x8;
typedef __attribute__((ext_vector_type(4))) float f32x4;

#define B_N   4
#define C_IN  32
#define C_OUT 64
#define S_H   32
#define S_W   64
#define S_D   64
#define HWD   (S_H * S_W * S_D)   /* 131072 */

__device__ __forceinline__ ushort f2bf(float f) {
    unsigned u = __builtin_bit_cast(unsigned, f);
    unsigned r = (u + 0x7FFFu + ((u >> 16) & 1u)) >> 16;  // RNE
    return (ushort)r;
}

// Implicit-GEMM conv3d: M=co(64), N=(4 w)x(64 d)=256 per block, K=28taps*32ci.
// One MFMA k-step (K=32) = 4 taps (quad) x 8 ci (j); ci is LDS-fastest so both
// fragments load with a single ds_read_b128.
__global__ __launch_bounds__(256) void conv3d_mfma_kernel(
    const float* __restrict__ X, const float* __restrict__ Wt,
    const float* __restrict__ bias, float* __restrict__ out)
{
    __shared__ ushort Xs[3 * 6 * 66 * 8];   // [hh][ww][dpos][ci8]  19008 B
    __shared__ ushort Ws[28 * 64 * 8];      // [tap][co][ci8]       28672 B

    const int tid  = threadIdx.x;
    const int lane = tid & 63;
    const int wave = tid >> 6;
    const int nl   = lane & 15;   // n (d) index within 16-tile / m index for A
    const int quad = lane >> 4;   // selects tap within k-step; row group for C/D
    const int co_base = wave * 16;

    const int blk = blockIdx.x;       // 2048 blocks = (b4, h32, wt16)
    const int wt  = blk & 15;
    const int h   = (blk >> 4) & 31;
    const int b   = blk >> 9;
    const int w0  = wt * 4;

    float bs[4];
    #pragma unroll
    for (int r = 0; r < 4; ++r) bs[r] = bias[co_base + quad * 4 + r];

    f32x4 acc[16];
    #pragma unroll
    for (int i = 0; i < 16; ++i) acc[i] = (f32x4){0.f, 0.f, 0.f, 0.f};

    for (int cic = 0; cic < 4; ++cic) {   // ci chunks of 8
        __syncthreads();

        // ---- stage weights: sites (co,t) = 64*27; 8 ci per site -> b128 write
        for (int s = tid; s < 64 * 27; s += 256) {
            int co = s / 27;
            int t  = s - co * 27;
            const float* wp = Wt + ((long)co * C_IN + cic * 8) * 27 + t;
            bf16x8 pk;
            #pragma unroll
            for (int j = 0; j < 8; ++j) pk[j] = (short)f2bf(wp[j * 27]);
            *(bf16x8*)&Ws[(t * 64 + co) * 8] = pk;
        }
        // zero-pad tap 27 (K padding: 27 real taps -> 28)
        for (int s = tid; s < 64; s += 256) {
            bf16x8 z;
            #pragma unroll
            for (int j = 0; j < 8; ++j) z[j] = 0;
            *(bf16x8*)&Ws[(27 * 64 + s) * 8] = z;
        }
        // ---- stage X: sites (hh,ww,dpos) = 3*6*66 = 1188; 8 ci per site
        for (int s = tid; s < 1188; s += 256) {
            int hh   = s / 396;           // 6*66
            int r0   = s - hh * 396;
            int ww   = r0 / 66;
            int dpos = r0 - ww * 66;
            int hp = h - 1 + hh;
            int wp2 = w0 - 1 + ww;
            int dp = dpos - 1;
            bool ok = (unsigned)hp < S_H && (unsigned)wp2 < S_W && (unsigned)dp < S_D;
            int hc = min(max(hp, 0), S_H - 1);
            int wc = min(max(wp2, 0), S_W - 1);
            int dc = min(max(dp, 0), S_D - 1);
            const float* xp = X + (((long)(b * C_IN + cic * 8) * S_H + hc) * S_W + wc) * S_D + dc;
            bf16x8 pk;
            #pragma unroll
            for (int j = 0; j < 8; ++j) {
                float v = xp[(long)j * HWD];          // clamped => always in-bounds
                pk[j] = ok ? (short)f2bf(v) : (short)0;
            }
            *(bf16x8*)&Xs[s * 8] = pk;
        }
        __syncthreads();

        // ---- compute: 7 tap-groups x 16 n-tiles
        #pragma unroll
        for (int tg = 0; tg < 7; ++tg) {
            int tap = tg * 4 + quad;
            bf16x8 afrag = *(const bf16x8*)&Ws[(tap * 64 + co_base + nl) * 8];
            int tb = tap < 27 ? tap : 0;   // pad tap reads tap0 (A is zero there)
            int kh = tb / 9;
            int r9 = tb - kh * 9;
            int kw = r9 / 3;
            int kd = r9 - kw * 3;
            int bbase = ((kh * 6 + kw) * 66 + kd + nl) * 8;
            #pragma unroll
            for (int wi = 0; wi < 4; ++wi) {
                #pragma unroll
                for (int dt = 0; dt < 4; ++dt) {
                    bf16x8 bfrag = *(const bf16x8*)&Xs[bbase + wi * (66 * 8) + dt * (16 * 8)];
                    acc[wi * 4 + dt] = __builtin_amdgcn_mfma_f32_16x16x32_bf16(
                        afrag, bfrag, acc[wi * 4 + dt], 0, 0, 0);
                }
            }
        }
    }

    // ---- epilogue: D[m=quad*4+r][n=nl], add bias, fp32 store
    #pragma unroll
    for (int wi = 0; wi < 4; ++wi) {
        int w = w0 + wi;
        #pragma unroll
        for (int dt = 0; dt < 4; ++dt) {
            int d0 = dt * 16 + nl;
            f32x4 a = acc[wi * 4 + dt];
            #pragma unroll
            for (int r = 0; r < 4; ++r) {
                int co = co_base + quad * 4 + r;
                out[(((long)(b * C_OUT + co) * S_H + h) * S_W + w) * S_D + d0] = a[r] + bs[r];
            }
        }
    }
}

extern "C" void kernel_launch(void* const* d_in, const int* in_sizes, int n_in,
                              void* d_out, int out_size, void* d_ws, size_t ws_size,
                              hipStream_t stream) {
    const float* X    = (const float*)d_in[0];
    const float* Wt   = (const float*)d_in[1];
    const float* bias = (const float*)d_in[2];
    float* out = (float*)d_out;
    conv3d_mfma_kernel<<<dim3(2048), dim3(256), 0, stream>>>(X, Wt, bias, out);
}

// Round 2
// 272.436 us; speedup vs baseline: 1.5586x; 1.5586x over previous
//
#include <hip/hip_runtime.h>
#include <hip/hip_bf16.h>

typedef __attribute__((ext_vector_type(8))) short bf16x8;
typedef __attribute__((ext_vector_type(4))) float f32x4;

#define B_N   4
#define C_IN  32
#define C_OUT 64
#define S_H   32
#define S_W   64
#define S_D   64
#define HWD   (S_H * S_W * S_D)   /* 131072 */

// ws layout: Wpk [4cic][28tap][64co][8ci] bf16 = 229376 B, then
//            Xpk [4cic][4b][32h][64w][64d][8ci] bf16 = 33554432 B
#define WPK_USHORTS (4 * 28 * 64 * 8)          /* 57344  */
#define XPK_OFF_USHORTS WPK_USHORTS            /* 16B-aligned: 57344*2/16=7168 */
#define WS_NEEDED ((size_t)(WPK_USHORTS + 4UL * 4 * 32 * 64 * 64 * 8) * 2)

__device__ __forceinline__ ushort f2bf(float f) {
    unsigned u = __builtin_bit_cast(unsigned, f);
    unsigned r = (u + 0x7FFFu + ((u >> 16) & 1u)) >> 16;  // RNE
    return (ushort)r;
}

// ---- prep: pack weights into per-chunk LDS image --------------------------
__global__ __launch_bounds__(256) void pack_w_kernel(
    const float* __restrict__ Wt, ushort* __restrict__ Wpk)
{
    int idx = blockIdx.x * 256 + threadIdx.x;       // 4*28*64 = 7168
    int cic = idx / 1792;
    int r   = idx - cic * 1792;
    int tap = r >> 6;
    int co  = r & 63;
    bf16x8 pk;
    #pragma unroll
    for (int j = 0; j < 8; ++j)
        pk[j] = (tap < 27) ? (short)f2bf(Wt[((long)co * C_IN + cic * 8 + j) * 27 + tap])
                           : (short)0;
    *((bf16x8*)Wpk + idx) = pk;
}

// ---- prep: transpose+convert X to [cic][b][h][w][d][ci8] bf16 -------------
__global__ __launch_bounds__(256) void pack_x_kernel(
    const float* __restrict__ X, ushort* __restrict__ Xpk)
{
    long idx = (long)blockIdx.x * 256 + threadIdx.x;  // 2^21
    int d   = idx & 63;
    int w   = (idx >> 6) & 63;
    int h   = (idx >> 12) & 31;
    int b   = (idx >> 17) & 3;
    int cic = (idx >> 19) & 3;
    const float* xp = X + (((long)(b * C_IN + cic * 8) * S_H + h) * S_W + w) * S_D + d;
    bf16x8 pk;
    #pragma unroll
    for (int j = 0; j < 8; ++j) pk[j] = (short)f2bf(xp[(long)j * HWD]);
    *((bf16x8*)Xpk + idx) = pk;
}

// ---- main: implicit-GEMM conv3d ------------------------------------------
// M=co(64), N=(4 w)x(64 d)=256 per block, K=28taps*32ci.
// One MFMA k-step (K=32) = 4 taps (quad) x 8 ci (j).
__global__ __launch_bounds__(256) void conv3d_mfma_kernel(
    const ushort* __restrict__ Xpk, const ushort* __restrict__ Wpk,
    const float* __restrict__ bias, float* __restrict__ out)
{
    __shared__ ushort Xs[3 * 6 * 66 * 8];   // [hh][ww][dpos][ci8]  19008 B
    __shared__ ushort Ws[28 * 64 * 8];      // [tap][co][ci8]       28672 B

    const int tid  = threadIdx.x;
    const int lane = tid & 63;
    const int wave = tid >> 6;
    const int nl   = lane & 15;
    const int quad = lane >> 4;
    const int co_base = wave * 16;

    const int blk = blockIdx.x;       // 2048 blocks = (b4, h32, wt16)
    const int wt  = blk & 15;
    const int h   = (blk >> 4) & 31;
    const int b   = blk >> 9;
    const int w0  = wt * 4;

    float bs[4];
    #pragma unroll
    for (int r = 0; r < 4; ++r) bs[r] = bias[co_base + quad * 4 + r];

    f32x4 acc[16];
    #pragma unroll
    for (int i = 0; i < 16; ++i) acc[i] = (f32x4){0.f, 0.f, 0.f, 0.f};

    for (int cic = 0; cic < 4; ++cic) {   // ci chunks of 8
        __syncthreads();

        // ---- stage weights: linear b128 copy of pre-packed chunk (1792 vecs)
        {
            const bf16x8* src = (const bf16x8*)Wpk + cic * 1792;
            #pragma unroll
            for (int k = 0; k < 7; ++k) {
                int s = tid + k * 256;
                *(bf16x8*)&Ws[s * 8] = src[s];
            }
        }
        // ---- stage X: 1188 sites, one b128 load + one b128 LDS write each
        {
            const bf16x8* xc = (const bf16x8*)Xpk + ((long)cic * 4 + b) * (32 * 64 * 64);
            for (int s = tid; s < 1188; s += 256) {
                int hh   = s / 396;           // 6*66
                int r0   = s - hh * 396;
                int ww   = r0 / 66;
                int dpos = r0 - ww * 66;
                int hp  = h - 1 + hh;
                int wp2 = w0 - 1 + ww;
                int dp  = dpos - 1;
                bool ok = (unsigned)hp < S_H && (unsigned)wp2 < S_W && (unsigned)dp < S_D;
                int hc = min(max(hp, 0), S_H - 1);
                int wc = min(max(wp2, 0), S_W - 1);
                int dc = min(max(dp, 0), S_D - 1);
                bf16x8 v = xc[((long)hc * S_W + wc) * S_D + dc];
                if (!ok) {
                    #pragma unroll
                    for (int j = 0; j < 8; ++j) v[j] = 0;
                }
                *(bf16x8*)&Xs[s * 8] = v;
            }
        }
        __syncthreads();

        // ---- compute: 7 tap-groups x 16 n-tiles
        #pragma unroll
        for (int tg = 0; tg < 7; ++tg) {
            int tap = tg * 4 + quad;
            bf16x8 afrag = *(const bf16x8*)&Ws[(tap * 64 + co_base + nl) * 8];
            int tb = tap < 27 ? tap : 0;   // pad tap reads tap0 (A is zero there)
            int kh = tb / 9;
            int r9 = tb - kh * 9;
            int kw = r9 / 3;
            int kd = r9 - kw * 3;
            int bbase = ((kh * 6 + kw) * 66 + kd + nl) * 8;
            #pragma unroll
            for (int wi = 0; wi < 4; ++wi) {
                #pragma unroll
                for (int dt = 0; dt < 4; ++dt) {
                    bf16x8 bfrag = *(const bf16x8*)&Xs[bbase + wi * (66 * 8) + dt * (16 * 8)];
                    acc[wi * 4 + dt] = __builtin_amdgcn_mfma_f32_16x16x32_bf16(
                        afrag, bfrag, acc[wi * 4 + dt], 0, 0, 0);
                }
            }
        }
    }

    // ---- epilogue: D[m=quad*4+r][n=nl], add bias, fp32 store
    #pragma unroll
    for (int wi = 0; wi < 4; ++wi) {
        int w = w0 + wi;
        #pragma unroll
        for (int dt = 0; dt < 4; ++dt) {
            int d0 = dt * 16 + nl;
            f32x4 a = acc[wi * 4 + dt];
            #pragma unroll
            for (int r = 0; r < 4; ++r) {
                int co = co_base + quad * 4 + r;
                out[(((long)(b * C_OUT + co) * S_H + h) * S_W + w) * S_D + d0] = a[r] + bs[r];
            }
        }
    }
}

// ---- fallback (round-1 path, no workspace needed) -------------------------
__global__ __launch_bounds__(256) void conv3d_mfma_fallback(
    const float* __restrict__ X, const float* __restrict__ Wt,
    const float* __restrict__ bias, float* __restrict__ out)
{
    __shared__ ushort Xs[3 * 6 * 66 * 8];
    __shared__ ushort Ws[28 * 64 * 8];

    const int tid  = threadIdx.x;
    const int lane = tid & 63;
    const int wave = tid >> 6;
    const int nl   = lane & 15;
    const int quad = lane >> 4;
    const int co_base = wave * 16;

    const int blk = blockIdx.x;
    const int wt  = blk & 15;
    const int h   = (blk >> 4) & 31;
    const int b   = blk >> 9;
    const int w0  = wt * 4;

    float bs[4];
    #pragma unroll
    for (int r = 0; r < 4; ++r) bs[r] = bias[co_base + quad * 4 + r];

    f32x4 acc[16];
    #pragma unroll
    for (int i = 0; i < 16; ++i) acc[i] = (f32x4){0.f, 0.f, 0.f, 0.f};

    for (int cic = 0; cic < 4; ++cic) {
        __syncthreads();
        for (int s = tid; s < 64 * 27; s += 256) {
            int co = s / 27;
            int t  = s - co * 27;
            const float* wp = Wt + ((long)co * C_IN + cic * 8) * 27 + t;
            bf16x8 pk;
            #pragma unroll
            for (int j = 0; j < 8; ++j) pk[j] = (short)f2bf(wp[j * 27]);
            *(bf16x8*)&Ws[(t * 64 + co) * 8] = pk;
        }
        for (int s = tid; s < 64; s += 256) {
            bf16x8 z;
            #pragma unroll
            for (int j = 0; j < 8; ++j) z[j] = 0;
            *(bf16x8*)&Ws[(27 * 64 + s) * 8] = z;
        }
        for (int s = tid; s < 1188; s += 256) {
            int hh   = s / 396;
            int r0   = s - hh * 396;
            int ww   = r0 / 66;
            int dpos = r0 - ww * 66;
            int hp = h - 1 + hh;
            int wp2 = w0 - 1 + ww;
            int dp = dpos - 1;
            bool ok = (unsigned)hp < S_H && (unsigned)wp2 < S_W && (unsigned)dp < S_D;
            int hc = min(max(hp, 0), S_H - 1);
            int wc = min(max(wp2, 0), S_W - 1);
            int dc = min(max(dp, 0), S_D - 1);
            const float* xp = X + (((long)(b * C_IN + cic * 8) * S_H + hc) * S_W + wc) * S_D + dc;
            bf16x8 pk;
            #pragma unroll
            for (int j = 0; j < 8; ++j) {
                float v = xp[(long)j * HWD];
                pk[j] = ok ? (short)f2bf(v) : (short)0;
            }
            *(bf16x8*)&Xs[s * 8] = pk;
        }
        __syncthreads();

        #pragma unroll
        for (int tg = 0; tg < 7; ++tg) {
            int tap = tg * 4 + quad;
            bf16x8 afrag = *(const bf16x8*)&Ws[(tap * 64 + co_base + nl) * 8];
            int tb = tap < 27 ? tap : 0;
            int kh = tb / 9;
            int r9 = tb - kh * 9;
            int kw = r9 / 3;
            int kd = r9 - kw * 3;
            int bbase = ((kh * 6 + kw) * 66 + kd + nl) * 8;
            #pragma unroll
            for (int wi = 0; wi < 4; ++wi) {
                #pragma unroll
                for (int dt = 0; dt < 4; ++dt) {
                    bf16x8 bfrag = *(const bf16x8*)&Xs[bbase + wi * (66 * 8) + dt * (16 * 8)];
                    acc[wi * 4 + dt] = __builtin_amdgcn_mfma_f32_16x16x32_bf16(
                        afrag, bfrag, acc[wi * 4 + dt], 0, 0, 0);
                }
            }
        }
    }

    #pragma unroll
    for (int wi = 0; wi < 4; ++wi) {
        int w = w0 + wi;
        #pragma unroll
        for (int dt = 0; dt < 4; ++dt) {
            int d0 = dt * 16 + nl;
            f32x4 a = acc[wi * 4 + dt];
            #pragma unroll
            for (int r = 0; r < 4; ++r) {
                int co = co_base + quad * 4 + r;
                out[(((long)(b * C_OUT + co) * S_H + h) * S_W + w) * S_D + d0] = a[r] + bs[r];
            }
        }
    }
}

extern "C" void kernel_launch(void* const* d_in, const int* in_sizes, int n_in,
                              void* d_out, int out_size, void* d_ws, size_t ws_size,
                              hipStream_t stream) {
    const float* X    = (const float*)d_in[0];
    const float* Wt   = (const float*)d_in[1];
    const float* bias = (const float*)d_in[2];
    float* out = (float*)d_out;

    if (ws_size >= WS_NEEDED) {
        ushort* Wpk = (ushort*)d_ws;
        ushort* Xpk = (ushort*)d_ws + XPK_OFF_USHORTS;
        pack_w_kernel<<<dim3(28),   dim3(256), 0, stream>>>(Wt, Wpk);
        pack_x_kernel<<<dim3(8192), dim3(256), 0, stream>>>(X, Xpk);
        conv3d_mfma_kernel<<<dim3(2048), dim3(256), 0, stream>>>(Xpk, Wpk, bias, out);
    } else {
        conv3d_mfma_fallback<<<dim3(2048), dim3(256), 0, stream>>>(X, Wt, bias, out);
    }
}

// Round 3
// 231.755 us; speedup vs baseline: 1.8322x; 1.1755x over previous
//
#include <hip/hip_runtime.h>
#include <hip/hip_bf16.h>

typedef __attribute__((ext_vector_type(8))) short bf16x8;
typedef __attribute__((ext_vector_type(4))) float f32x4;

#define B_N   4
#define C_IN  32
#define C_OUT 64
#define S_H   32
#define S_W   64
#define S_D   64
#define HWD   (S_H * S_W * S_D)   /* 131072 */

// ws layout (ushorts): [Wpk 4*28*64*8][zeropage 2048][Xpk 4*4*32*64*64*8]
#define WPK_USHORTS     (4 * 28 * 64 * 8)              /* 57344 */
#define ZP_OFF_USHORTS  WPK_USHORTS
#define XPK_OFF_USHORTS (WPK_USHORTS + 2048)           /* 118784 B: 16B aligned */
#define XPK_USHORTS     (4UL * 4 * 32 * 64 * 64 * 8)
#define WS_NEEDED       ((size_t)(XPK_OFF_USHORTS + XPK_USHORTS) * 2)

__device__ __forceinline__ ushort f2bf(float f) {
    unsigned u = __builtin_bit_cast(unsigned, f);
    unsigned r = (u + 0x7FFFu + ((u >> 16) & 1u)) >> 16;  // RNE
    return (ushort)r;
}

typedef const __attribute__((address_space(1))) unsigned int* dma_gptr;
typedef __attribute__((address_space(3))) unsigned int* dma_lptr;

__device__ __forceinline__ void dma16(const void* g, void* l) {
    __builtin_amdgcn_global_load_lds((dma_gptr)g, (dma_lptr)l, 16, 0, 0);
}

// ---- prep: pack weights [cic][tap28][co64][ci8] bf16; also zero the zero-page
__global__ __launch_bounds__(256) void pack_w_kernel(
    const float* __restrict__ Wt, ushort* __restrict__ Wpk, ushort* __restrict__ Zp)
{
    int idx = blockIdx.x * 256 + threadIdx.x;       // 4*28*64 = 7168
    int cic = idx / 1792;
    int r   = idx - cic * 1792;
    int tap = r >> 6;
    int co  = r & 63;
    bf16x8 pk;
    #pragma unroll
    for (int j = 0; j < 8; ++j)
        pk[j] = (tap < 27) ? (short)f2bf(Wt[((long)co * C_IN + cic * 8 + j) * 27 + tap])
                           : (short)0;
    *((bf16x8*)Wpk + idx) = pk;
    if (blockIdx.x == 0) {
        bf16x8 z;
        #pragma unroll
        for (int j = 0; j < 8; ++j) z[j] = 0;
        *((bf16x8*)Zp + threadIdx.x) = z;           // 256*16B = 4KB zero page
    }
}

// ---- prep: transpose+convert X to [cic][b][h][w][d][ci8] bf16 -------------
__global__ __launch_bounds__(256) void pack_x_kernel(
    const float* __restrict__ X, ushort* __restrict__ Xpk)
{
    long idx = (long)blockIdx.x * 256 + threadIdx.x;  // 2^21
    int d   = idx & 63;
    int w   = (idx >> 6) & 63;
    int h   = (idx >> 12) & 31;
    int b   = (idx >> 17) & 3;
    int cic = (idx >> 19) & 3;
    const float* xp = X + (((long)(b * C_IN + cic * 8) * S_H + h) * S_W + w) * S_D + d;
    bf16x8 pk;
    #pragma unroll
    for (int j = 0; j < 8; ++j) pk[j] = (short)f2bf(xp[(long)j * HWD]);
    *((bf16x8*)Xpk + idx) = pk;
}

// ---- main: implicit-GEMM conv3d ------------------------------------------
// Block tile 64co x 256n (4w x 64d). Each wave: 64co x 64n (its own w column),
// 4 m-tiles x 4 n-tiles of 16x16x32 MFMA -> 4 A + 4 B ds_read_b128 per k-step
// feeding 16 MFMAs (operand bytes/FLOP = 1/32, LDS-balanced).
// All staging via global_load_lds(16B); X double-buffered, W per chunk.
__global__ __launch_bounds__(256, 2) void conv3d_mfma_kernel(
    const ushort* __restrict__ Xpk, const ushort* __restrict__ Wpk,
    const ushort* __restrict__ Zp,
    const float* __restrict__ bias, float* __restrict__ out)
{
    __shared__ ushort Xs[2][1280 * 8];   // [hh3][ww6][dpos66][ci8] + pad, 20480 B each
    __shared__ ushort Ws[1792 * 8];      // [tap28][co64][ci8]            28672 B

    const int tid  = threadIdx.x;
    const int lane = tid & 63;
    const int wave = tid >> 6;
    const int nl   = lane & 15;
    const int quad = lane >> 4;

    const int blk = blockIdx.x;       // 2048 blocks = (b4, h32, wt16)
    const int wt  = blk & 15;
    const int h   = (blk >> 4) & 31;
    const int b   = blk >> 9;
    const int w0  = wt * 4;

    // ---- per-site X staging pointers (chunk 0) + per-chunk advance --------
    const ushort* gp[5];
    int adv[5];
    #pragma unroll
    for (int k = 0; k < 5; ++k) {
        int s = tid + k * 256;
        if (s < 1188) {
            int hh   = s / 396;           // 6*66
            int r0   = s - hh * 396;
            int ww   = r0 / 66;
            int dpos = r0 - ww * 66;
            int hp  = h - 1 + hh;
            int wp2 = w0 - 1 + ww;
            int dp  = dpos - 1;
            bool ok = (unsigned)hp < S_H && (unsigned)wp2 < S_W && (unsigned)dp < S_D;
            if (ok) {
                gp[k]  = Xpk + ((long)b * 131072 + ((long)hp * S_W + wp2) * S_D + dp) * 8;
                adv[k] = 4 * 131072 * 8;  // cic stride in ushorts
            } else { gp[k] = Zp; adv[k] = 0; }
        } else { gp[k] = Zp; adv[k] = 0; }   // pad sites [1188,1280)
    }

    // ---- per-tg LDS offsets (ushort units) --------------------------------
    int a_off[7], b_off[7];
    #pragma unroll
    for (int tg = 0; tg < 7; ++tg) {
        int tap = tg * 4 + quad;
        int tb  = tap < 27 ? tap : 0;      // pad tap: A rows are zero anyway
        int kh = tb / 9;
        int r9 = tb - kh * 9;
        int kw = r9 / 3;
        int kd = r9 - kw * 3;
        a_off[tg] = (tap * 64 + nl) * 8;
        b_off[tg] = (((kh * 6 + kw + wave) * 66) + kd + nl) * 8;  // ww = wave+kw
    }

    float bs[16];
    #pragma unroll
    for (int mi = 0; mi < 4; ++mi)
        #pragma unroll
        for (int r = 0; r < 4; ++r)
            bs[mi * 4 + r] = bias[mi * 16 + quad * 4 + r];

    f32x4 acc[16];
    #pragma unroll
    for (int i = 0; i < 16; ++i) acc[i] = (f32x4){0.f, 0.f, 0.f, 0.f};

    // prologue: DMA X chunk 0 into buf 0
    #pragma unroll
    for (int k = 0; k < 5; ++k)
        dma16(gp[k], &Xs[0][(tid + k * 256) * 8]);

    for (int cic = 0; cic < 4; ++cic) {
        __syncthreads();                 // drains X[cic] DMA; prev compute done

        // stage W chunk (DMA, L2-resident source)
        {
            const ushort* src = Wpk + (long)cic * 1792 * 8;
            #pragma unroll
            for (int k = 0; k < 7; ++k) {
                int s = tid + k * 256;
                dma16(src + s * 8, &Ws[s * 8]);
            }
        }
        __syncthreads();                 // drains W DMA only

        // prefetch X chunk cic+1 (drained at next top barrier, behind compute)
        if (cic < 3) {
            #pragma unroll
            for (int k = 0; k < 5; ++k)
                dma16(gp[k] + (long)(cic + 1) * adv[k],
                      &Xs[(cic + 1) & 1][(tid + k * 256) * 8]);
        }

        const ushort* xb = Xs[cic & 1];
        #pragma unroll
        for (int tg = 0; tg < 7; ++tg) {
            bf16x8 af[4], bf[4];
            #pragma unroll
            for (int mi = 0; mi < 4; ++mi)
                af[mi] = *(const bf16x8*)&Ws[a_off[tg] + mi * 128];   // +mi*16 co
            #pragma unroll
            for (int dt = 0; dt < 4; ++dt)
                bf[dt] = *(const bf16x8*)&xb[b_off[tg] + dt * 128];   // +dt*16 d
            #pragma unroll
            for (int mi = 0; mi < 4; ++mi)
                #pragma unroll
                for (int dt = 0; dt < 4; ++dt)
                    acc[mi * 4 + dt] = __builtin_amdgcn_mfma_f32_16x16x32_bf16(
                        af[mi], bf[dt], acc[mi * 4 + dt], 0, 0, 0);
        }
    }

    // ---- epilogue: co = mi*16 + quad*4 + r, n = (w0+wave, dt*16+nl) -------
    const int w = w0 + wave;
    #pragma unroll
    for (int mi = 0; mi < 4; ++mi) {
        #pragma unroll
        for (int dt = 0; dt < 4; ++dt) {
            f32x4 a = acc[mi * 4 + dt];
            int d0 = dt * 16 + nl;
            #pragma unroll
            for (int r = 0; r < 4; ++r) {
                int co = mi * 16 + quad * 4 + r;
                out[(((long)(b * C_OUT + co) * S_H + h) * S_W + w) * S_D + d0]
                    = a[r] + bs[mi * 4 + r];
            }
        }
    }
}

// ---- fallback (round-1 path, no workspace needed) -------------------------
__global__ __launch_bounds__(256) void conv3d_mfma_fallback(
    const float* __restrict__ X, const float* __restrict__ Wt,
    const float* __restrict__ bias, float* __restrict__ out)
{
    __shared__ ushort Xs[3 * 6 * 66 * 8];
    __shared__ ushort Ws[28 * 64 * 8];

    const int tid  = threadIdx.x;
    const int lane = tid & 63;
    const int wave = tid >> 6;
    const int nl   = lane & 15;
    const int quad = lane >> 4;
    const int co_base = wave * 16;

    const int blk = blockIdx.x;
    const int wt  = blk & 15;
    const int h   = (blk >> 4) & 31;
    const int b   = blk >> 9;
    const int w0  = wt * 4;

    float bs[4];
    #pragma unroll
    for (int r = 0; r < 4; ++r) bs[r] = bias[co_base + quad * 4 + r];

    f32x4 acc[16];
    #pragma unroll
    for (int i = 0; i < 16; ++i) acc[i] = (f32x4){0.f, 0.f, 0.f, 0.f};

    for (int cic = 0; cic < 4; ++cic) {
        __syncthreads();
        for (int s = tid; s < 64 * 27; s += 256) {
            int co = s / 27;
            int t  = s - co * 27;
            const float* wp = Wt + ((long)co * C_IN + cic * 8) * 27 + t;
            bf16x8 pk;
            #pragma unroll
            for (int j = 0; j < 8; ++j) pk[j] = (short)f2bf(wp[j * 27]);
            *(bf16x8*)&Ws[(t * 64 + co) * 8] = pk;
        }
        for (int s = tid; s < 64; s += 256) {
            bf16x8 z;
            #pragma unroll
            for (int j = 0; j < 8; ++j) z[j] = 0;
            *(bf16x8*)&Ws[(27 * 64 + s) * 8] = z;
        }
        for (int s = tid; s < 1188; s += 256) {
            int hh   = s / 396;
            int r0   = s - hh * 396;
            int ww   = r0 / 66;
            int dpos = r0 - ww * 66;
            int hp = h - 1 + hh;
            int wp2 = w0 - 1 + ww;
            int dp = dpos - 1;
            bool ok = (unsigned)hp < S_H && (unsigned)wp2 < S_W && (unsigned)dp < S_D;
            int hc = min(max(hp, 0), S_H - 1);
            int wc = min(max(wp2, 0), S_W - 1);
            int dc = min(max(dp, 0), S_D - 1);
            const float* xp = X + (((long)(b * C_IN + cic * 8) * S_H + hc) * S_W + wc) * S_D + dc;
            bf16x8 pk;
            #pragma unroll
            for (int j = 0; j < 8; ++j) {
                float v = xp[(long)j * HWD];
                pk[j] = ok ? (short)f2bf(v) : (short)0;
            }
            *(bf16x8*)&Xs[s * 8] = pk;
        }
        __syncthreads();

        #pragma unroll
        for (int tg = 0; tg < 7; ++tg) {
            int tap = tg * 4 + quad;
            bf16x8 afrag = *(const bf16x8*)&Ws[(tap * 64 + co_base + nl) * 8];
            int tb = tap < 27 ? tap : 0;
            int kh = tb / 9;
            int r9 = tb - kh * 9;
            int kw = r9 / 3;
            int kd = r9 - kw * 3;
            int bbase = ((kh * 6 + kw) * 66 + kd + nl) * 8;
            #pragma unroll
            for (int wi = 0; wi < 4; ++wi) {
                #pragma unroll
                for (int dt = 0; dt < 4; ++dt) {
                    bf16x8 bfrag = *(const bf16x8*)&Xs[bbase + wi * (66 * 8) + dt * (16 * 8)];
                    acc[wi * 4 + dt] = __builtin_amdgcn_mfma_f32_16x16x32_bf16(
                        afrag, bfrag, acc[wi * 4 + dt], 0, 0, 0);
                }
            }
        }
    }

    #pragma unroll
    for (int wi = 0; wi < 4; ++wi) {
        int w = w0 + wi;
        #pragma unroll
        for (int dt = 0; dt < 4; ++dt) {
            int d0 = dt * 16 + nl;
            f32x4 a = acc[wi * 4 + dt];
            #pragma unroll
            for (int r = 0; r < 4; ++r) {
                int co = co_base + quad * 4 + r;
                out[(((long)(b * C_OUT + co) * S_H + h) * S_W + w) * S_D + d0] = a[r] + bs[r];
            }
        }
    }
}

extern "C" void kernel_launch(void* const* d_in, const int* in_sizes, int n_in,
                              void* d_out, int out_size, void* d_ws, size_t ws_size,
                              hipStream_t stream) {
    const float* X    = (const float*)d_in[0];
    const float* Wt   = (const float*)d_in[1];
    const float* bias = (const float*)d_in[2];
    float* out = (float*)d_out;

    if (ws_size >= WS_NEEDED) {
        ushort* Wpk = (ushort*)d_ws;
        ushort* Zp  = (ushort*)d_ws + ZP_OFF_USHORTS;
        ushort* Xpk = (ushort*)d_ws + XPK_OFF_USHORTS;
        pack_w_kernel<<<dim3(28),   dim3(256), 0, stream>>>(Wt, Wpk, Zp);
        pack_x_kernel<<<dim3(8192), dim3(256), 0, stream>>>(X, Xpk);
        conv3d_mfma_kernel<<<dim3(2048), dim3(256), 0, stream>>>(Xpk, Wpk, Zp, bias, out);
    } else {
        conv3d_mfma_fallback<<<dim3(2048), dim3(256), 0, stream>>>(X, Wt, bias, out);
    }
}